// Round 5
// baseline (388.768 us; speedup 1.0000x reference)
//
#include <hip/hip_runtime.h>
#include <hip/hip_bf16.h>
#include <cfloat>

// Problem constants (reference: B=4, L=4096, D=1024, H=16, Dh=64)
#define BB 4
#define LL 4096
#define DD 1024
#define HH 16
#define DHH 64
#define MM (BB * LL)          // 16384 rows
#define LN_EPS 1e-5f
#define LDQVG 3072            // fused q|v|g row stride
#define SCC 16                // scan chunk length
#define NCHUNK (LL / SCC)     // 256 chunks per batch

typedef __hip_bfloat16 bf16;
typedef __attribute__((ext_vector_type(8))) short short8;
typedef __attribute__((ext_vector_type(4))) float f32x4;

struct bf16x4 { bf16 a, b, c, d; };
struct alignas(16) bf8 { bf16 e[8]; };

__device__ __forceinline__ float b2f(bf16 u) {
    union { unsigned int i; float f; } c;
    c.i = ((unsigned int)__bfloat16_as_ushort(u)) << 16;
    return c.f;
}

__device__ __forceinline__ float lam_of(const float* beta, int head) {
    float lam = 1.0f - exp2f(-beta[head]);
    return fminf(fmaxf(lam, 1.1754944e-38f), 1.0f - 1e-9f);
}

// ---------------------------------------------------------------------------
// All f32->bf16 conversions in ONE dispatch: x (16384 blocks) then the four
// weight matrices (4*1024 blocks) into contiguous wq|wv|wg|wo.
// ---------------------------------------------------------------------------
__global__ __launch_bounds__(256) void cvt_all(const float* __restrict__ x,
                                               const float* __restrict__ wq,
                                               const float* __restrict__ wv,
                                               const float* __restrict__ wg,
                                               const float* __restrict__ wo,
                                               bf16* __restrict__ xb,
                                               bf16* __restrict__ wb) {
    const int blk = blockIdx.x;
    const float* src;
    bf16* dst;
    size_t off;
    if (blk < 16384) {
        src = x; dst = xb; off = (size_t)blk * 1024;
    } else {
        int wblk  = blk - 16384;
        int which = wblk >> 10;
        src = (which == 0) ? wq : (which == 1) ? wv : (which == 2) ? wg : wo;
        dst = wb + (size_t)which * 1048576;
        off = (size_t)(wblk & 1023) * 1024;
    }
    size_t i = off + threadIdx.x * 4;
    float4 f = *(const float4*)(src + i);
    bf16x4 o;
    o.a = __float2bfloat16(f.x);
    o.b = __float2bfloat16(f.y);
    o.c = __float2bfloat16(f.z);
    o.d = __float2bfloat16(f.w);
    *(bf16x4*)(dst + i) = o;
}

// ---------------------------------------------------------------------------
// async 16B global -> LDS. NOTE: imm offset applies to BOTH global and LDS
// addresses — always pass 0, advance global pointers manually.
// ---------------------------------------------------------------------------
__device__ __forceinline__ void async16(const bf16* g, bf16* l) {
    __builtin_amdgcn_global_load_lds(
        (const __attribute__((address_space(1))) void*)g,
        (__attribute__((address_space(3))) void*)l,
        16, 0, 0);
}

// ---------------------------------------------------------------------------
// GEMM: C[M,N] = A[M,K] * B[N,K]^T  (row-major, K contiguous), ldc row stride.
//
// R5 structure: 256x128 block tile, 256 threads = 4 waves (2M x 2N), each
// wave 128x64 output = 8x4 of v_mfma_f32_16x16x32_bf16 (acc 128 f32/lane).
//
//  - A: LDS ring-3 of BK=32 slots (16KB each) = 48 KB total. Staging via
//    global_load_lds with the R1-verified swizzle (phys 16B-chunk =
//    logical ^ ((row>>1)&3)), zero bank conflicts for the 16x16 read
//    pattern (row = mult16 + (lane&15), chunk = lane>>4) [R4: measured 0].
//  - B: NOT in LDS (R5 change). Weights are 6MB/2MB, L2/L3-hot and shared
//    by all blocks; each wave loads its 4 B-fragments per tile straight
//    from global into VGPRs (16 rows x 64B footprint -> 16x64B segments,
//    same coalescing as staged loads, L1/L2-served). This cuts per-tile
//    LDS traffic 72KB -> 48KB per block-tile and drops B's swizzle.
//    b-register waits are compiler-managed (pure dataflow); MFMA is
//    ni-outer so only b[0] gates the first 8 MFMAs (staged vmcnt waits).
//  - ONE raw s_barrier per K-tile; counted vmcnt. Ring audit: stage of
//    tile T+2 targets slot (T-1), read-complete before barrier(T-1).
//    The compiler's pre-MFMA b-wait (b issued after stage(T+1) in program
//    order of tile T-1... b newest) retires stage(T+1) as a side effect;
//    the explicit end-of-tile vmcnt(4) is the hard guarantee that A(T+1)
//    is retired before the barrier publishes it.
// ---------------------------------------------------------------------------
template <typename OutT, int KK>
__global__ __launch_bounds__(256, 2) void gemm_ring(const bf16* __restrict__ A,
                                                    const bf16* __restrict__ Bm,
                                                    OutT* __restrict__ C,
                                                    int ldc) {
    constexpr int BK    = 32;
    constexpr int NT    = KK / BK;        // 32 K-tiles
    constexpr int ASLOT = 256 * BK;       // 8192 elems = 16 KB

    __shared__ alignas(16) bf16 sA[3 * ASLOT];   // 48 KB

    const int t    = threadIdx.x;
    const int lane = t & 63;
    const int wave = t >> 6;
    const int wm   = wave >> 1;          // 0..1 (M half: 128 rows)
    const int wn   = wave & 1;           // 0..1 (N half: 64 cols)
    const int bm   = blockIdx.x;
    const int bn   = blockIdx.y;

    // ---- A staging: thread t owns phys chunk t&3 of row t>>2 (+j*64 rows).
    const int srow = t >> 2;
    const int cswz = ((t & 3) ^ ((srow >> 1) & 3)) * 8;
    const bf16* gA = A + (size_t)(bm * 256 + srow) * KK + cswz;
    const size_t rstep = (size_t)64 * KK;        // +64 rows
    bf16* const lA = sA + t * 8;

    // ---- A ds_read (R1-verified zero-conflict 16x16 pattern):
    // row = base16 + (lane&15), logical chunk = lane>>4,
    // phys = logical ^ (((lane&15)>>1)&3).
    const int f16  = lane & 15;
    const int swz8 = ((lane >> 4) ^ ((f16 >> 1) & 3)) * 8;
    const bf16* const rdA0 = sA + (wm * 128 + f16) * BK + swz8;  // +mi*512

    // ---- B direct from global: row = bn*128 + wn*64 + ni*16 + (lane&15),
    // k-chunk = lane>>4 (no swizzle needed on the register path).
    const bf16* gB = Bm + (size_t)(bn * 128 + wn * 64 + f16) * KK
                   + (size_t)((lane >> 4) * 8);
    const size_t nstep = (size_t)16 * KK;        // +16 N-rows

    f32x4 acc[8][4] = {};

    // slot element-offsets: slR = slot(T), slS = slot(T+2) (rotate mod 3)
    int slR = 0;
    int slS = 2 * ASLOT;

    // ---- prologue: stage A tiles 0,1; retire tile 0 (vmcnt 8->4); publish.
#pragma unroll
    for (int j = 0; j < 4; ++j) async16(gA + j * rstep, lA + j * 2048);
    gA += BK;
#pragma unroll
    for (int j = 0; j < 4; ++j) async16(gA + j * rstep, lA + ASLOT + j * 2048);
    gA += BK;
    asm volatile("s_waitcnt vmcnt(4)" ::: "memory");
    __builtin_amdgcn_s_barrier();

#define TILE(DOSTAGE, VMN)                                                     \
  {                                                                            \
    short8 b[4];                                                               \
    _Pragma("unroll") for (int ni = 0; ni < 4; ++ni)                           \
        b[ni] = *(const short8*)(gB + ni * nstep);                             \
    gB += BK;                                                                  \
    short8 a[8];                                                               \
    _Pragma("unroll") for (int mi = 0; mi < 8; ++mi)                           \
        a[mi] = *(const short8*)(rdA0 + mi * 512 + slR);                       \
    if (DOSTAGE) {                                                             \
      _Pragma("unroll") for (int j = 0; j < 4; ++j)                            \
          async16(gA + j * rstep, lA + slS + j * 2048);                        \
      gA += BK;                                                                \
    }                                                                          \
    __builtin_amdgcn_s_setprio(1);                                             \
    _Pragma("unroll") for (int ni = 0; ni < 4; ++ni)                           \
      _Pragma("unroll") for (int mi = 0; mi < 8; ++mi)                         \
        acc[mi][ni] = __builtin_amdgcn_mfma_f32_16x16x32_bf16(                 \
            a[mi], b[ni], acc[mi][ni], 0, 0, 0);                               \
    __builtin_amdgcn_s_setprio(0);                                             \
    if ((VMN) == 4)      asm volatile("s_waitcnt vmcnt(4)" ::: "memory");      \
    else if ((VMN) == 0) asm volatile("s_waitcnt vmcnt(0)" ::: "memory");      \
    if ((VMN) >= 0) __builtin_amdgcn_s_barrier();                              \
    slR = (slR == 2 * ASLOT) ? 0 : slR + ASLOT;                                \
    slS = (slS == 2 * ASLOT) ? 0 : slS + ASLOT;                                \
  }

    // main loop: T = 0..NT-3 stage tiles 2..NT-1, counted vmcnt(4)
#pragma unroll 1
    for (int T = 0; T < NT - 2; ++T) {
        TILE(true, 4);
    }
    TILE(false, 0);    // T = NT-2: drain remaining A stage
    TILE(false, -1);   // T = NT-1: no sync, fall through to epilogue

#undef TILE

    // epilogue: 16x16 C/D layout: col = lane&15, row = (lane>>4)*4 + reg
    const int col0 = bn * 128 + wn * 64 + (lane & 15);
    const int row0 = bm * 256 + wm * 128 + ((lane >> 4) * 4);
#pragma unroll
    for (int mi = 0; mi < 8; ++mi) {
#pragma unroll
        for (int ni = 0; ni < 4; ++ni) {
#pragma unroll
            for (int r = 0; r < 4; ++r) {
                int row = row0 + mi * 16 + r;
                C[(size_t)row * ldc + col0 + ni * 16] = (OutT)acc[mi][ni][r];
            }
        }
    }
}

// ---------------------------------------------------------------------------
// Exact two-phase retention scan over fused qvg layout (row stride 3072).
// Phase A: per-chunk local scan -> chunk sums S.
// Phase B: carry scan over chunks (8-wide prefetch pipeline).
// Phase C (fused with LN+gate below): re-scan from carry, LN, gate, write z.
// ---------------------------------------------------------------------------
__global__ __launch_bounds__(64) void scan_chunksum(const bf16* __restrict__ qvg,
                                                    const float* __restrict__ beta,
                                                    float* __restrict__ S) {
    const int c    = blockIdx.x;
    const int half = blockIdx.y;
    const int b    = blockIdx.z;
    const int tid  = threadIdx.x;
    const int dh0  = half * 512 + tid * 8;
    const float lam = lam_of(beta, dh0 >> 6);

    const bf16* vp = qvg + 1024 + ((size_t)(b * LL + c * SCC)) * LDQVG + dh0;

    float s[8] = {};
#pragma unroll
    for (int t = 0; t < SCC; ++t) {
        bf8 vv = *(const bf8*)(vp + (size_t)t * LDQVG);
#pragma unroll
        for (int j = 0; j < 8; ++j)
            s[j] = fmaf(s[j], lam, b2f(vv.e[j]));
    }

    float* sp = S + ((size_t)(b * NCHUNK + c)) * DD + dh0;
    float4 lo = {s[0], s[1], s[2], s[3]};
    float4 hi = {s[4], s[5], s[6], s[7]};
    *(float4*)(sp)     = lo;
    *(float4*)(sp + 4) = hi;
}

// Serial carry over 256 chunks, 8-wide load prefetch to break the
// latency chain (loads for batch i+1 are independent of the t-recurrence).
__global__ __launch_bounds__(64) void scan_carry(const float* __restrict__ S,
                                                 float* __restrict__ T,
                                                 const float* __restrict__ beta) {
    const int gid = blockIdx.x * 64 + threadIdx.x;  // 0..4095
    const int b = gid >> 10;
    const int f = gid & 1023;
    const float lam  = lam_of(beta, f >> 6);
    const float lamC = powf(lam, (float)SCC);

    const size_t base = (size_t)b * NCHUNK * DD + f;

    float v[8];
#pragma unroll
    for (int j = 0; j < 8; ++j) v[j] = S[base + (size_t)j * DD];

    float t = 0.0f;
    for (int c0 = 0; c0 < NCHUNK; c0 += 8) {
        float cur[8];
#pragma unroll
        for (int j = 0; j < 8; ++j) cur[j] = v[j];
        if (c0 + 8 < NCHUNK) {
#pragma unroll
            for (int j = 0; j < 8; ++j)
                v[j] = S[base + (size_t)(c0 + 8 + j) * DD];
        }
#pragma unroll
        for (int j = 0; j < 8; ++j) {
            T[base + (size_t)(c0 + j) * DD] = t;
            t = fmaf(t, lamC, cur[j]);
        }
    }
}

// ---------------------------------------------------------------------------
// Fused: re-scan chunk from carry T -> ret (kept in LDS), per-row LayerNorm,
// SiLU gate, write z (bf16, contiguous [M,1024]). ret never touches HBM.
// grid (NCHUNK, BB), 128 threads (2 waves). LDS 16 rows x 1024 bf16 = 32KB.
// R5: phase-2 gate loads hoisted into a 16-load prefetch burst (previously
// 2 HBM loads per row sat serially on the per-row critical path).
// ---------------------------------------------------------------------------
__global__ __launch_bounds__(128) void scan_apply_ln(const bf16* __restrict__ qvg,
                                                     const float* __restrict__ beta,
                                                     const float* __restrict__ T,
                                                     const float* __restrict__ gamma,
                                                     const float* __restrict__ betaln,
                                                     bf16* __restrict__ z) {
    __shared__ bf16 lds_ret[SCC][DD];   // 32 KB

    const int c   = blockIdx.x;
    const int b   = blockIdx.y;
    const int tid = threadIdx.x;        // 0..127
    const int f0  = tid * 8;
    const float lam = lam_of(beta, f0 >> 6);

    // ---- phase 1: local scan from carry, ret -> LDS ----
    const float* tp = T + ((size_t)(b * NCHUNK + c)) * DD + f0;
    float4 lo = *(const float4*)(tp);
    float4 hi = *(const float4*)(tp + 4);
    float s[8] = {lo.x, lo.y, lo.z, lo.w, hi.x, hi.y, hi.z, hi.w};

    const bf16* qp = qvg + ((size_t)(b * LL + c * SCC)) * LDQVG + f0;
#pragma unroll
    for (int t = 0; t < SCC; ++t) {
        const size_t off = (size_t)t * LDQVG;
        bf8 vv = *(const bf8*)(qp + 1024 + off);
        bf8 qq = *(const bf8*)(qp + off);
        bf8 o;
#pragma unroll
        for (int j = 0; j < 8; ++j) {
            s[j] = fmaf(s[j], lam, b2f(vv.e[j]));
            o.e[j] = __float2bfloat16(b2f(qq.e[j]) * s[j]);
        }
        *(bf8*)(&lds_ret[t][f0]) = o;
    }
    __syncthreads();

    // ---- phase 2: per-row LN + SiLU gate. wave w does rows w, w+2, ... ----
    const int lane = tid & 63;
    const int wv   = tid >> 6;

    // prefetch gate rows for all 8 iterations (independent HBM loads)
    bf8 gAp[8], gBp[8];
#pragma unroll
    for (int i = 0; i < 8; ++i) {
        const size_t row = (size_t)(b * LL + c * SCC + wv + 2 * i);
        const bf16* gp = qvg + row * LDQVG + 2048 + lane * 8;
        gAp[i] = *(const bf8*)(gp);
        gBp[i] = *(const bf8*)(gp + 512);
    }

    // cache gamma/beta for this lane's two feature groups (lane*8, 512+lane*8)
    float gmA[8], btA[8], gmB[8], btB[8];
#pragma unroll
    for (int j = 0; j < 8; j += 4) {
        *(float4*)(gmA + j) = *(const float4*)(gamma  + lane * 8 + j);
        *(float4*)(btA + j) = *(const float4*)(betaln + lane * 8 + j);
        *(float4*)(gmB + j) = *(const float4*)(gamma  + 512 + lane * 8 + j);
        *(float4*)(btB + j) = *(const float4*)(betaln + 512 + lane * 8 + j);
    }

#pragma unroll
    for (int i = 0; i < 8; ++i) {
        const int t = wv + 2 * i;
        bf8 rA = *(const bf8*)(&lds_ret[t][lane * 8]);
        bf8 rB = *(const bf8*)(&lds_ret[t][512 + lane * 8]);

        float xa[8], xb2[8];
        float sum = 0.f, sq = 0.f;
#pragma unroll
        for (int j = 0; j < 8; ++j) {
            xa[j]  = b2f(rA.e[j]);
            xb2[j] = b2f(rB.e[j]);
            sum += xa[j] + xb2[j];
            sq  += xa[j] * xa[j] + xb2[j] * xb2[j];
        }
#pragma unroll
        for (int off = 32; off >= 1; off >>= 1) {
            sum += __shfl_xor(sum, off, 64);
            sq  += __shfl_xor(sq,  off, 64);
        }
        const float mu   = sum * (1.0f / DD);
        const float var  = sq * (1.0f / DD) - mu * mu;
        const float rstd = rsqrtf(var + LN_EPS);

        bf8 oA, oB;
#pragma unroll
        for (int j = 0; j < 8; ++j) {
            float ya = (xa[j]  - mu) * rstd * gmA[j] + btA[j];
            float yb = (xb2[j] - mu) * rstd * gmB[j] + btB[j];
            float ga = b2f(gAp[i].e[j]);
            float gb = b2f(gBp[i].e[j]);
            oA.e[j] = __float2bfloat16(ya * (ga / (1.0f + expf(-ga))));
            oB.e[j] = __float2bfloat16(yb * (gb / (1.0f + expf(-gb))));
        }
        const size_t row = (size_t)(b * LL + c * SCC + t);
        bf16* zp = z + row * DD + lane * 8;
        *(bf8*)(zp)       = oA;
        *(bf8*)(zp + 512) = oB;
    }
}

// ---------------------------------------------------------------------------
// launch
// ---------------------------------------------------------------------------
extern "C" void kernel_launch(void* const* d_in, const int* in_sizes, int n_in,
                              void* d_out, int out_size, void* d_ws, size_t ws_size,
                              hipStream_t stream) {
    const float* x     = (const float*)d_in[0];
    const float* Wq    = (const float*)d_in[1];
    const float* Wv    = (const float*)d_in[2];
    const float* Wo    = (const float*)d_in[3];
    const float* Wg    = (const float*)d_in[4];
    const float* beta  = (const float*)d_in[5];
    const float* ln_g  = (const float*)d_in[6];
    const float* ln_b  = (const float*)d_in[7];
    float* out = (float*)d_out;

    char* ws = (char*)d_ws;
    // workspace (136MB total, time-multiplexed):
    //   @0    : xb 32MB (cvt -> QVG GEMM)  ->  S 4MB (chunksum -> carry)
    //           -> zb 32MB (apply_ln -> final GEMM)
    //   @32MB : wqb 6MB (wq|wv|wg; dead after QVG GEMM) -> T 4MB (carry -> apply)
    //   @38MB : wob 2MB (live until final GEMM)
    //   @40MB : qvg 96MB [M,3072] = q|v|g per row
    bf16*  xb   = (bf16*)ws;
    float* Sbuf = (float*)ws;                                  // alias xb (dead)
    bf16*  wqb  = (bf16*)(ws + (size_t)32 * 1024 * 1024);
    float* Tbuf = (float*)(ws + (size_t)32 * 1024 * 1024);     // alias wqb (dead)
    bf16*  wob  = wqb + 3 * 1048576;
    bf16*  qvg  = (bf16*)(ws + (size_t)40 * 1024 * 1024);
    bf16*  zb   = xb;

    // all dtype conversions in one dispatch (x + 4 weights)
    cvt_all<<<dim3(16384 + 4096), dim3(256), 0, stream>>>(x, Wq, Wv, Wg, Wo, xb, wqb);

    // fused QVG GEMM: [M,1024] x [3072,1024]^T -> [M,3072]
    gemm_ring<bf16, DD><<<dim3(MM / 256, LDQVG / 128), dim3(256), 0, stream>>>(
        xb, wqb, qvg, LDQVG);

    // exact two-phase retention scan + fused LN/gate
    scan_chunksum<<<dim3(NCHUNK, 2, BB), dim3(64), 0, stream>>>(qvg, beta, Sbuf);
    scan_carry<<<dim3(64), dim3(64), 0, stream>>>(Sbuf, Tbuf, beta);
    scan_apply_ln<<<dim3(NCHUNK, BB), dim3(128), 0, stream>>>(
        qvg, beta, Tbuf, ln_g, ln_b, zb);

    // final GEMM: [M,1024] x [1024,1024]^T -> [M,1024] f32
    gemm_ring<float, DD><<<dim3(MM / 256, DD / 128), dim3(256), 0, stream>>>(
        zb, wob, out, DD);
}

// Round 7
// 329.583 us; speedup vs baseline: 1.1796x; 1.1796x over previous
//
#include <hip/hip_runtime.h>
#include <hip/hip_bf16.h>
#include <cfloat>

// Problem constants (reference: B=4, L=4096, D=1024, H=16, Dh=64)
#define BB 4
#define LL 4096
#define DD 1024
#define HH 16
#define DHH 64
#define MM (BB * LL)          // 16384 rows
#define LN_EPS 1e-5f
#define LDQVG 3072            // fused q|v|g row stride
#define SCC 16                // scan chunk length
#define NCHUNK (LL / SCC)     // 256 chunks per batch

typedef __hip_bfloat16 bf16;
typedef __attribute__((ext_vector_type(8))) short short8;
typedef __attribute__((ext_vector_type(4))) float f32x4;

struct bf16x4 { bf16 a, b, c, d; };
struct alignas(16) bf8 { bf16 e[8]; };

__device__ __forceinline__ float b2f(bf16 u) {
    union { unsigned int i; float f; } c;
    c.i = ((unsigned int)__bfloat16_as_ushort(u)) << 16;
    return c.f;
}

__device__ __forceinline__ float lam_of(const float* beta, int head) {
    float lam = 1.0f - exp2f(-beta[head]);
    return fminf(fmaxf(lam, 1.1754944e-38f), 1.0f - 1e-9f);
}

// ---------------------------------------------------------------------------
// All f32->bf16 conversions in ONE dispatch: x (16384 blocks) then the four
// weight matrices (4*1024 blocks) into contiguous wq|wv|wg|wo.
// ---------------------------------------------------------------------------
__global__ __launch_bounds__(256) void cvt_all(const float* __restrict__ x,
                                               const float* __restrict__ wq,
                                               const float* __restrict__ wv,
                                               const float* __restrict__ wg,
                                               const float* __restrict__ wo,
                                               bf16* __restrict__ xb,
                                               bf16* __restrict__ wb) {
    const int blk = blockIdx.x;
    const float* src;
    bf16* dst;
    size_t off;
    if (blk < 16384) {
        src = x; dst = xb; off = (size_t)blk * 1024;
    } else {
        int wblk  = blk - 16384;
        int which = wblk >> 10;
        src = (which == 0) ? wq : (which == 1) ? wv : (which == 2) ? wg : wo;
        dst = wb + (size_t)which * 1048576;
        off = (size_t)(wblk & 1023) * 1024;
    }
    size_t i = off + threadIdx.x * 4;
    float4 f = *(const float4*)(src + i);
    bf16x4 o;
    o.a = __float2bfloat16(f.x);
    o.b = __float2bfloat16(f.y);
    o.c = __float2bfloat16(f.z);
    o.d = __float2bfloat16(f.w);
    *(bf16x4*)(dst + i) = o;
}

// ---------------------------------------------------------------------------
// async 16B global -> LDS. NOTE: imm offset applies to BOTH global and LDS
// addresses — always pass 0, advance global pointers manually.
// ---------------------------------------------------------------------------
__device__ __forceinline__ void async16(const bf16* g, bf16* l) {
    __builtin_amdgcn_global_load_lds(
        (const __attribute__((address_space(1))) void*)g,
        (__attribute__((address_space(3))) void*)l,
        16, 0, 0);
}

// ---------------------------------------------------------------------------
// GEMM: C[M,N] = A[M,K] * B[N,K]^T  (row-major, K contiguous), ldc row stride.
//
// EXACT R4 structure (proven: 109us QVG, MfmaUtil 42, bank conflicts 0):
// 256x128 block tile, 256 threads = 4 waves (2M x 2N), wave 128x64 via
// 8x4 of v_mfma_f32_16x16x32_bf16 (acc 128 f32/lane).
//  - LDS ring-3 of BK=32 slots: A 16KB + B 8KB = 72KB -> 2 blocks/CU.
//  - ONE raw s_barrier per K-tile; counted vmcnt(6) steady state.
//  - swizzle: phys 16B-chunk = logical ^ ((row>>1)&3), 64B rows; read with
//    the 16x16 pattern (row = mult16 + (lane&15), chunk = lane>>4) = zero
//    conflicts (R1/R4 measured). Pre-swizzled global source + linear LDS
//    dest + swizzled ds_read (both-sides involution).
//
// R7 addition (non-GEMM lever): for the QVG launch, the V-column blocks
// (bn in [8,16)) ALSO emit the per-chunk decay-weighted sums
//   S[b][chunk][f] = sum_p lam^(15-p) * v[p]
// straight from the f32 accumulators — replaces the scan_chunksum kernel
// (32MB re-read + a dispatch). Lane l holds intra-chunk positions
// p = (l>>4)*4 + r of chunk wm*8+mi; 4 fmas + shfl_xor(16,32) reduce;
// lanes 0-15 write 64B-contiguous f32 segments. S lives in d_out (dead
// until the final GEMM, which overwrites every element).
// ---------------------------------------------------------------------------
template <typename OutT, int KK>
__global__ __launch_bounds__(256, 2) void gemm_ring(const bf16* __restrict__ A,
                                                    const bf16* __restrict__ Bm,
                                                    OutT* __restrict__ C,
                                                    int ldc,
                                                    float* __restrict__ Sout,
                                                    const float* __restrict__ beta) {
    constexpr int BK    = 32;
    constexpr int NT    = KK / BK;        // 32 K-tiles
    constexpr int ASLOT = 256 * BK;       // 8192 elems = 16 KB
    constexpr int BSLOT = 128 * BK;       // 4096 elems =  8 KB

    __shared__ alignas(16) bf16 sA[3 * ASLOT];   // 48 KB
    __shared__ alignas(16) bf16 sB[3 * BSLOT];   // 24 KB

    const int t    = threadIdx.x;
    const int lane = t & 63;
    const int wave = t >> 6;
    const int wm   = wave >> 1;          // 0..1 (M half: 128 rows)
    const int wn   = wave & 1;           // 0..1 (N half: 64 cols)
    const int bm   = blockIdx.x;
    const int bn   = blockIdx.y;

    // ---- staging: thread t owns phys chunk t&3 of row t>>2 (+j*64 rows).
    const int srow = t >> 2;
    const int cswz = ((t & 3) ^ ((srow >> 1) & 3)) * 8;
    const bf16* gA = A  + (size_t)(bm * 256 + srow) * KK + cswz;
    const bf16* gB = Bm + (size_t)(bn * 128 + srow) * KK + cswz;
    const size_t rstep = (size_t)64 * KK;        // +64 rows
    bf16* const lA = sA + t * 8;
    bf16* const lB = sB + t * 8;

    // ---- ds_read addressing (R1/R4-verified zero-conflict 16x16 pattern)
    const int f16  = lane & 15;
    const int swz8 = ((lane >> 4) ^ ((f16 >> 1) & 3)) * 8;
    const bf16* const rdA0 = sA + (wm * 128 + f16) * BK + swz8;  // +mi*512
    const bf16* const rdB0 = sB + (wn * 64  + f16) * BK + swz8;  // +ni*512

    f32x4 acc[8][4] = {};

    // slot element-offsets: slR = slot(T), slS = slot(T+2) (rotate mod 3)
    int slR = 0,         slR2 = 0;
    int slS = 2 * ASLOT, slS2 = 2 * BSLOT;

    // ---- prologue: stage tiles 0,1; retire tile 0 (vmcnt 12->6); publish.
#pragma unroll
    for (int j = 0; j < 4; ++j) async16(gA + j * rstep, lA + j * 2048);
#pragma unroll
    for (int j = 0; j < 2; ++j) async16(gB + j * rstep, lB + j * 2048);
    gA += BK; gB += BK;
#pragma unroll
    for (int j = 0; j < 4; ++j) async16(gA + j * rstep, lA + ASLOT + j * 2048);
#pragma unroll
    for (int j = 0; j < 2; ++j) async16(gB + j * rstep, lB + BSLOT + j * 2048);
    gA += BK; gB += BK;
    asm volatile("s_waitcnt vmcnt(6)" ::: "memory");
    __builtin_amdgcn_s_barrier();

#define TILE(DOSTAGE, VMN)                                                     \
  {                                                                            \
    short8 a[8], b[4];                                                         \
    a[0] = *(const short8*)(rdA0 + slR);                                       \
    _Pragma("unroll") for (int ni = 0; ni < 4; ++ni)                           \
        b[ni] = *(const short8*)(rdB0 + ni * 512 + slR2);                      \
    _Pragma("unroll") for (int mi = 1; mi < 8; ++mi)                           \
        a[mi] = *(const short8*)(rdA0 + mi * 512 + slR);                       \
    if (DOSTAGE) {                                                             \
      _Pragma("unroll") for (int j = 0; j < 4; ++j)                            \
          async16(gA + j * rstep, lA + slS + j * 2048);                        \
      _Pragma("unroll") for (int j = 0; j < 2; ++j)                            \
          async16(gB + j * rstep, lB + slS2 + j * 2048);                       \
      gA += BK; gB += BK;                                                      \
    }                                                                          \
    __builtin_amdgcn_s_setprio(1);                                             \
    _Pragma("unroll") for (int mi = 0; mi < 8; ++mi)                           \
      _Pragma("unroll") for (int ni = 0; ni < 4; ++ni)                         \
        acc[mi][ni] = __builtin_amdgcn_mfma_f32_16x16x32_bf16(                 \
            a[mi], b[ni], acc[mi][ni], 0, 0, 0);                               \
    __builtin_amdgcn_s_setprio(0);                                             \
    if ((VMN) == 6)      asm volatile("s_waitcnt vmcnt(6)" ::: "memory");      \
    else if ((VMN) == 0) asm volatile("s_waitcnt vmcnt(0)" ::: "memory");      \
    if ((VMN) >= 0) __builtin_amdgcn_s_barrier();                              \
    slR  = (slR  == 2 * ASLOT) ? 0 : slR  + ASLOT;                             \
    slR2 = (slR2 == 2 * BSLOT) ? 0 : slR2 + BSLOT;                             \
    slS  = (slS  == 2 * ASLOT) ? 0 : slS  + ASLOT;                             \
    slS2 = (slS2 == 2 * BSLOT) ? 0 : slS2 + BSLOT;                             \
  }

    // main loop: T = 0..NT-3 stage tiles 2..NT-1, counted vmcnt(6)
#pragma unroll 1
    for (int T = 0; T < NT - 2; ++T) {
        TILE(true, 6);
    }
    TILE(false, 0);    // T = NT-2: drain tile NT-1's loads
    TILE(false, -1);   // T = NT-1: no sync, fall through to epilogue

#undef TILE

    // epilogue: 16x16 C/D layout: col = lane&15, row = (lane>>4)*4 + reg
    const int col0 = bn * 128 + wn * 64 + (lane & 15);
    const int row0 = bm * 256 + wm * 128 + ((lane >> 4) * 4);
#pragma unroll
    for (int mi = 0; mi < 8; ++mi) {
#pragma unroll
        for (int ni = 0; ni < 4; ++ni) {
#pragma unroll
            for (int r = 0; r < 4; ++r) {
                int row = row0 + mi * 16 + r;
                C[(size_t)row * ldc + col0 + ni * 16] = (OutT)acc[mi][ni][r];
            }
        }
    }

    // ---- fused chunk-sum epilogue (QVG launch, V columns only) ----
    if (Sout && bn >= 8 && bn < 16) {
        const int p0 = (lane >> 4) * 4;            // intra-chunk base position
        const int bglob = bm >> 4;                 // batch (4096 rows = 16 bm)
        const int c0 = ((bm & 15) * 16 + wm * 8);  // chunk idx of mi=0
#pragma unroll
        for (int ni = 0; ni < 4; ++ni) {
            const int f = col0 + ni * 16 - 1024;   // v-feature index [0,1024)
            const float lam = lam_of(beta, f >> 6);
            const float l2g = __log2f(lam);
            float w[4];
#pragma unroll
            for (int r = 0; r < 4; ++r)
                w[r] = exp2f((float)(15 - p0 - r) * l2g);
#pragma unroll
            for (int mi = 0; mi < 8; ++mi) {
                float part = 0.0f;
#pragma unroll
                for (int r = 0; r < 4; ++r)
                    part = fmaf(w[r], acc[mi][ni][r], part);
                part += __shfl_xor(part, 16, 64);
                part += __shfl_xor(part, 32, 64);
                if (p0 == 0) {                     // lanes 0..15 write
                    const int cg = c0 + mi;
                    Sout[((size_t)bglob * NCHUNK + cg) * DD + f] = part;
                }
            }
        }
    }
}

// ---------------------------------------------------------------------------
// Serial carry over 256 chunks: T[c] = scan of chunk sums S with factor
// lam^SCC. 16-wide load prefetch (R7: was 8) halves the serial HBM-latency
// batches; loads for batch i+1 are independent of the t-recurrence.
// ---------------------------------------------------------------------------
__global__ __launch_bounds__(64) void scan_carry(const float* __restrict__ S,
                                                 float* __restrict__ T,
                                                 const float* __restrict__ beta) {
    const int gid = blockIdx.x * 64 + threadIdx.x;  // 0..4095
    const int b = gid >> 10;
    const int f = gid & 1023;
    const float lam  = lam_of(beta, f >> 6);
    const float lamC = powf(lam, (float)SCC);

    const size_t base = (size_t)b * NCHUNK * DD + f;

    float v[16];
#pragma unroll
    for (int j = 0; j < 16; ++j) v[j] = S[base + (size_t)j * DD];

    float t = 0.0f;
    for (int c0 = 0; c0 < NCHUNK; c0 += 16) {
        float cur[16];
#pragma unroll
        for (int j = 0; j < 16; ++j) cur[j] = v[j];
        if (c0 + 16 < NCHUNK) {
#pragma unroll
            for (int j = 0; j < 16; ++j)
                v[j] = S[base + (size_t)(c0 + 16 + j) * DD];
        }
#pragma unroll
        for (int j = 0; j < 16; ++j) {
            T[base + (size_t)(c0 + j) * DD] = t;
            t = fmaf(t, lamC, cur[j]);
        }
    }
}

// ---------------------------------------------------------------------------
// Fused: re-scan chunk from carry T -> ret (kept in LDS), per-row LayerNorm,
// SiLU gate, write z (bf16, contiguous [M,1024]). ret never touches HBM.
// grid (NCHUNK, BB), 128 threads (2 waves). LDS 16 rows x 1024 bf16 = 32KB.
// R7: phase-1 q/v loads one-row-ahead prefetch (breaks load->fma serial
// exposure); phase-2 gate loads prefetched in a 16-load burst (R5).
// ---------------------------------------------------------------------------
__global__ __launch_bounds__(128) void scan_apply_ln(const bf16* __restrict__ qvg,
                                                     const float* __restrict__ beta,
                                                     const float* __restrict__ T,
                                                     const float* __restrict__ gamma,
                                                     const float* __restrict__ betaln,
                                                     bf16* __restrict__ z) {
    __shared__ bf16 lds_ret[SCC][DD];   // 32 KB

    const int c   = blockIdx.x;
    const int b   = blockIdx.y;
    const int tid = threadIdx.x;        // 0..127
    const int f0  = tid * 8;
    const float lam = lam_of(beta, f0 >> 6);

    // ---- phase 1: local scan from carry, ret -> LDS ----
    const float* tp = T + ((size_t)(b * NCHUNK + c)) * DD + f0;
    float4 lo = *(const float4*)(tp);
    float4 hi = *(const float4*)(tp + 4);
    float s[8] = {lo.x, lo.y, lo.z, lo.w, hi.x, hi.y, hi.z, hi.w};

    const bf16* qp = qvg + ((size_t)(b * LL + c * SCC)) * LDQVG + f0;
    bf8 vv = *(const bf8*)(qp + 1024);
    bf8 qq = *(const bf8*)(qp);
#pragma unroll
    for (int t = 0; t < SCC; ++t) {
        bf8 vn, qn;
        if (t + 1 < SCC) {
            const size_t offn = (size_t)(t + 1) * LDQVG;
            vn = *(const bf8*)(qp + 1024 + offn);
            qn = *(const bf8*)(qp + offn);
        }
        bf8 o;
#pragma unroll
        for (int j = 0; j < 8; ++j) {
            s[j] = fmaf(s[j], lam, b2f(vv.e[j]));
            o.e[j] = __float2bfloat16(b2f(qq.e[j]) * s[j]);
        }
        *(bf8*)(&lds_ret[t][f0]) = o;
        if (t + 1 < SCC) { vv = vn; qq = qn; }
    }
    __syncthreads();

    // ---- phase 2: per-row LN + SiLU gate. wave w does rows w, w+2, ... ----
    const int lane = tid & 63;
    const int wv   = tid >> 6;

    // prefetch gate rows for all 8 iterations (independent HBM loads)
    bf8 gAp[8], gBp[8];
#pragma unroll
    for (int i = 0; i < 8; ++i) {
        const size_t row = (size_t)(b * LL + c * SCC + wv + 2 * i);
        const bf16* gp = qvg + row * LDQVG + 2048 + lane * 8;
        gAp[i] = *(const bf8*)(gp);
        gBp[i] = *(const bf8*)(gp + 512);
    }

    // cache gamma/beta for this lane's two feature groups (lane*8, 512+lane*8)
    float gmA[8], btA[8], gmB[8], btB[8];
#pragma unroll
    for (int j = 0; j < 8; j += 4) {
        *(float4*)(gmA + j) = *(const float4*)(gamma  + lane * 8 + j);
        *(float4*)(btA + j) = *(const float4*)(betaln + lane * 8 + j);
        *(float4*)(gmB + j) = *(const float4*)(gamma  + 512 + lane * 8 + j);
        *(float4*)(btB + j) = *(const float4*)(betaln + 512 + lane * 8 + j);
    }

#pragma unroll
    for (int i = 0; i < 8; ++i) {
        const int t = wv + 2 * i;
        bf8 rA = *(const bf8*)(&lds_ret[t][lane * 8]);
        bf8 rB = *(const bf8*)(&lds_ret[t][512 + lane * 8]);

        float xa[8], xb2[8];
        float sum = 0.f, sq = 0.f;
#pragma unroll
        for (int j = 0; j < 8; ++j) {
            xa[j]  = b2f(rA.e[j]);
            xb2[j] = b2f(rB.e[j]);
            sum += xa[j] + xb2[j];
            sq  += xa[j] * xa[j] + xb2[j] * xb2[j];
        }
#pragma unroll
        for (int off = 32; off >= 1; off >>= 1) {
            sum += __shfl_xor(sum, off, 64);
            sq  += __shfl_xor(sq,  off, 64);
        }
        const float mu   = sum * (1.0f / DD);
        const float var  = sq * (1.0f / DD) - mu * mu;
        const float rstd = rsqrtf(var + LN_EPS);

        bf8 oA, oB;
#pragma unroll
        for (int j = 0; j < 8; ++j) {
            float ya = (xa[j]  - mu) * rstd * gmA[j] + btA[j];
            float yb = (xb2[j] - mu) * rstd * gmB[j] + btB[j];
            float ga = b2f(gAp[i].e[j]);
            float gb = b2f(gBp[i].e[j]);
            oA.e[j] = __float2bfloat16(ya * (ga / (1.0f + expf(-ga))));
            oB.e[j] = __float2bfloat16(yb * (gb / (1.0f + expf(-gb))));
        }
        const size_t row = (size_t)(b * LL + c * SCC + t);
        bf16* zp = z + row * DD + lane * 8;
        *(bf8*)(zp)       = oA;
        *(bf8*)(zp + 512) = oB;
    }
}

// ---------------------------------------------------------------------------
// launch
// ---------------------------------------------------------------------------
extern "C" void kernel_launch(void* const* d_in, const int* in_sizes, int n_in,
                              void* d_out, int out_size, void* d_ws, size_t ws_size,
                              hipStream_t stream) {
    const float* x     = (const float*)d_in[0];
    const float* Wq    = (const float*)d_in[1];
    const float* Wv    = (const float*)d_in[2];
    const float* Wo    = (const float*)d_in[3];
    const float* Wg    = (const float*)d_in[4];
    const float* beta  = (const float*)d_in[5];
    const float* ln_g  = (const float*)d_in[6];
    const float* ln_b  = (const float*)d_in[7];
    float* out = (float*)d_out;

    char* ws = (char*)d_ws;
    // workspace (136MB, time-multiplexed):
    //   @0    : xb 32MB (cvt -> QVG GEMM) -> zb 32MB (apply_ln -> final GEMM)
    //   @32MB : wqb 6MB (wq|wv|wg; dead after QVG GEMM) -> T 4MB (carry->apply)
    //   @38MB : wob 2MB (live until final GEMM)
    //   @40MB : qvg 96MB [M,3072] = q|v|g per row
    // S (4MB f32) lives in d_out (64MB f32): written by the QVG GEMM epilogue,
    // consumed by scan_carry, dead before the final GEMM overwrites ALL of out.
    bf16*  xb   = (bf16*)ws;
    bf16*  wqb  = (bf16*)(ws + (size_t)32 * 1024 * 1024);
    float* Tbuf = (float*)(ws + (size_t)32 * 1024 * 1024);     // alias wqb (dead)
    bf16*  wob  = wqb + 3 * 1048576;
    bf16*  qvg  = (bf16*)(ws + (size_t)40 * 1024 * 1024);
    bf16*  zb   = xb;
    float* Sbuf = out;                                         // scratch in d_out

    // all dtype conversions in one dispatch (x + 4 weights)
    cvt_all<<<dim3(16384 + 4096), dim3(256), 0, stream>>>(x, Wq, Wv, Wg, Wo, xb, wqb);

    // fused QVG GEMM: [M,1024] x [3072,1024]^T -> [M,3072]; V-blocks also
    // emit chunk sums S directly from f32 accumulators (replaces chunksum).
    gemm_ring<bf16, DD><<<dim3(MM / 256, LDQVG / 128), dim3(256), 0, stream>>>(
        xb, wqb, qvg, LDQVG, Sbuf, beta);

    // carry scan over chunks, then fused re-scan + LN + gate
    scan_carry<<<dim3(64), dim3(64), 0, stream>>>(Sbuf, Tbuf, beta);
    scan_apply_ln<<<dim3(NCHUNK, BB), dim3(128), 0, stream>>>(
        qvg, beta, Tbuf, ln_g, ln_b, zb);

    // final GEMM: [M,1024] x [1024,1024]^T -> [M,1024] f32 (overwrites out)
    gemm_ring<float, DD><<<dim3(MM / 256, DD / 128), dim3(256), 0, stream>>>(
        zb, wob, out, DD, nullptr, nullptr);
}